// Round 6
// baseline (175.766 us; speedup 1.0000x reference)
//
#include <hip/hip_runtime.h>
#include <hip/hip_bf16.h>
#include <math.h>

// Problem constants (fixed by the reference)
#define NROWS   65536          // 16*4096 flattened rows
#define DIM     64             // embedding dim
#define KCODES  1024           // num embeddings
#define NBLOCKS (NROWS / 128)  // 512 mega-kernel blocks

typedef short short8 __attribute__((ext_vector_type(8)));   // 8 bf16 = 4 VGPR (MFMA A/B frag)
typedef float f32x4  __attribute__((ext_vector_type(4)));   // MFMA C/D frag

// Output layout (floats), reference return order:
//   out[0] loss | out[1..] quantized (N*D) | perplexity | indices (as float)
#define OUT_Q_OFF    ((size_t)1)
#define OUT_PERP_OFF ((size_t)(1 + (size_t)NROWS * DIM))
#define OUT_IDX_OFF  ((size_t)(2 + (size_t)NROWS * DIM))

// Workspace layout (bytes); zeroing done by normalize_w_kernel (stream-ordered)
#define WS_COUNTS 0                         // unsigned[1024]
#define WS_SSEC   4096                      // float   (global SSE accumulator)
#define WS_DONE   4100                      // unsigned (blocks-done counter)
#define WS_WN     8192                      // float wn[1024*64]
#define WS_SK     (WS_WN + KCODES*DIM*4)    // float sk[1024]
#define WS_WNH    (WS_SK + KCODES*4)        // ushort wnh[1024*64]
#define WS_WNL    (WS_WNH + KCODES*DIM*2)   // ushort wnl[1024*64]

__device__ __forceinline__ unsigned short bf16_rne(float f) {
  unsigned u = __float_as_uint(f);
  return (unsigned short)((u + 0x7FFFu + ((u >> 16) & 1u)) >> 16);
}
__device__ __forceinline__ float bf16f(unsigned short h) {
  return __uint_as_float(((unsigned)h) << 16);
}

// Normalize codebook + split to bf16 hi/lo + zero the mega-kernel's counters.
__global__ void __launch_bounds__(64) normalize_w_kernel(
    const float* __restrict__ w, float* __restrict__ wn, float* __restrict__ sk,
    unsigned short* __restrict__ wnh, unsigned short* __restrict__ wnl,
    unsigned* __restrict__ counts, float* __restrict__ sse_accum,
    unsigned* __restrict__ done) {
  const int k = blockIdx.x;   // one code per 64-lane wave
  const int d = threadIdx.x;
  if (d == 0) {
    counts[k] = 0u;                                   // 1024 blocks cover counts[1024]
    if (k == 0) { *sse_accum = 0.f; *done = 0u; }
  }
  float v = w[k * DIM + d];
  float ss = v * v;
  #pragma unroll
  for (int o = 32; o > 0; o >>= 1) ss += __shfl_xor(ss, o, 64);
  const float den = fmaxf(sqrtf(ss), 1e-12f);
  const float q = v / den;                 // true division: hug reference rounding
  wn[k * DIM + d] = q;
  const unsigned short h = bf16_rne(q);
  wnh[k * DIM + d] = h;
  wnl[k * DIM + d] = bf16_rne(q - bf16f(h));
  float s2 = q * q;
  #pragma unroll
  for (int o = 32; o > 0; o >>= 1) s2 += __shfl_xor(s2, o, 64);
  if (d == 0) sk[k] = s2;
}

// Mega-kernel: split-2 bf16 MFMA filter + block-local exact refine + all
// bookkeeping + last-block finalize. Block = 256 thr (4 waves) = 128 rows.
// Keys: high 22 bits of fp32(sk+4-2dot), low 10 = code. Queue iff top-2 within
// <2 quant bins (bin 4.88e-4 >> split-2 err ~2e-5); queued rows re-scanned
// exactly in fp32 before any output is written.
__global__ void __launch_bounds__(256) vq_mega_kernel(
    const float* __restrict__ x, const unsigned short* __restrict__ wnh,
    const unsigned short* __restrict__ wnl, const float* __restrict__ sk,
    const float* __restrict__ wn, float* __restrict__ out,
    unsigned* __restrict__ counts, float* __restrict__ sse_accum,
    unsigned* __restrict__ done) {
  // AB union: phase A: Ah=[0,4608) Al=[4608,9216) u32 (128 rows x 36 u32)
  //           phase B: buf b at b*4608: Bh=[+0,+2304) Bl=[+2304,+4608)
  __shared__ unsigned AB[9216];
  __shared__ float skb[2][64];     // sk + 4.0 per staged chunk
  __shared__ float c_arr[128];     // ||xn||^2 per row
  __shared__ float rowsse[128];    // per-row SSE (approx; exact for refined)
  __shared__ int   ib[128];        // per-row final idx
  __shared__ int   qlist[128];     // block-local refine queue (row_local)
  __shared__ int   qn_s;
  __shared__ int   islast;
  const int tid = threadIdx.x;
  const int lane = tid & 63, wave = tid >> 6;

  if (tid == 0) qn_s = 0;

  // ---- phase 1: threads 0..127 normalize one row each, split to bf16 hi/lo ----
  if (tid < 128) {
    const size_t row = (size_t)blockIdx.x * 128 + tid;
    const float4* xr = (const float4*)(x + row * DIM);
    float4 xv[16];
    float ss = 0.f;
    #pragma unroll
    for (int i = 0; i < 16; i++) {
      xv[i] = xr[i];
      ss += xv[i].x * xv[i].x + xv[i].y * xv[i].y + xv[i].z * xv[i].z + xv[i].w * xv[i].w;
    }
    const float inv = 1.0f / fmaxf(sqrtf(ss), 1e-12f);   // mul-normalize: filter only
    float c = 0.f;
    #pragma unroll
    for (int i = 0; i < 16; i++) {
      const float a0 = xv[i].x * inv, a1 = xv[i].y * inv;
      const float a2 = xv[i].z * inv, a3 = xv[i].w * inv;
      c += a0 * a0 + a1 * a1 + a2 * a2 + a3 * a3;
      const unsigned short h0 = bf16_rne(a0), h1 = bf16_rne(a1);
      const unsigned short h2 = bf16_rne(a2), h3 = bf16_rne(a3);
      const unsigned short l0 = bf16_rne(a0 - bf16f(h0)), l1 = bf16_rne(a1 - bf16f(h1));
      const unsigned short l2 = bf16_rne(a2 - bf16f(h2)), l3 = bf16_rne(a3 - bf16f(h3));
      AB[tid * 36 + 2 * i]            = (unsigned)h0 | ((unsigned)h1 << 16);
      AB[tid * 36 + 2 * i + 1]        = (unsigned)h2 | ((unsigned)h3 << 16);
      AB[4608 + tid * 36 + 2 * i]     = (unsigned)l0 | ((unsigned)l1 << 16);
      AB[4608 + tid * 36 + 2 * i + 1] = (unsigned)l2 | ((unsigned)l3 << 16);
    }
    c_arr[tid] = c;
  }
  __syncthreads();

  // ---- A fragments -> registers (A[m=lane&15][k=(lane>>4)*8+j]) ----
  short8 ah[2][2], al[2][2];
  #pragma unroll
  for (int rt = 0; rt < 2; rt++)
    #pragma unroll
    for (int kk = 0; kk < 2; kk++) {
      const int r = wave * 32 + rt * 16 + (lane & 15);
      ah[rt][kk] = *(const short8*)&AB[r * 36 + kk * 16 + (lane >> 4) * 4];
      al[rt][kk] = *(const short8*)&AB[4608 + r * 36 + kk * 16 + (lane >> 4) * 4];
    }
  __syncthreads();   // A region now dead -> becomes B double-buffer

  unsigned k1[8], k2[8];
  #pragma unroll
  for (int s = 0; s < 8; s++) { k1[s] = 0xFFFFFFFFu; k2[s] = 0xFFFFFFFFu; }

  // stage chunk 0 into buf 0
  {
    const int code = tid >> 2, q = tid & 3;
    const float4* gh = (const float4*)(wnh + (size_t)code * DIM + q * 16);
    const float4* gl = (const float4*)(wnl + (size_t)code * DIM + q * 16);
    float4* dh = (float4*)&AB[code * 36 + q * 8];
    float4* dl = (float4*)&AB[2304 + code * 36 + q * 8];
    dh[0] = gh[0]; dh[1] = gh[1];
    dl[0] = gl[0]; dl[1] = gl[1];
    if (tid < 64) skb[0][tid] = sk[tid] + 4.0f;
  }

  #pragma unroll 2
  for (int c = 0; c < 16; c++) {
    const int b = c & 1;
    __syncthreads();   // buf b fully staged; buf b^1 free to overwrite
    if (c < 15) {      // stage next chunk (loads fly during compute below)
      const int nb = b ^ 1;
      const int code = tid >> 2, q = tid & 3;
      const float4* gh = (const float4*)(wnh + (size_t)((c + 1) * 64 + code) * DIM + q * 16);
      const float4* gl = (const float4*)(wnl + (size_t)((c + 1) * 64 + code) * DIM + q * 16);
      float4* dh = (float4*)&AB[nb * 4608 + code * 36 + q * 8];
      float4* dl = (float4*)&AB[nb * 4608 + 2304 + code * 36 + q * 8];
      dh[0] = gh[0]; dh[1] = gh[1];
      dl[0] = gl[0]; dl[1] = gl[1];
      if (tid < 64) skb[nb][tid] = sk[(c + 1) * 64 + tid] + 4.0f;
    }
    #pragma unroll
    for (int tt = 0; tt < 4; tt++) {
      const int cb = tt * 16 + (lane & 15);       // code within chunk (B col)
      const float skv4 = skb[b][cb];
      const unsigned codev = (unsigned)(c * 64 + cb);
      const short8 bh0 = *(const short8*)&AB[b * 4608 + cb * 36 + 0 * 16 + (lane >> 4) * 4];
      const short8 bh1 = *(const short8*)&AB[b * 4608 + cb * 36 + 1 * 16 + (lane >> 4) * 4];
      const short8 bl0 = *(const short8*)&AB[b * 4608 + 2304 + cb * 36 + 0 * 16 + (lane >> 4) * 4];
      const short8 bl1 = *(const short8*)&AB[b * 4608 + 2304 + cb * 36 + 1 * 16 + (lane >> 4) * 4];
      #pragma unroll
      for (int rt = 0; rt < 2; rt++) {
        f32x4 acc = {0.f, 0.f, 0.f, 0.f};
        acc = __builtin_amdgcn_mfma_f32_16x16x32_bf16(ah[rt][0], bh0, acc, 0, 0, 0);
        acc = __builtin_amdgcn_mfma_f32_16x16x32_bf16(ah[rt][1], bh1, acc, 0, 0, 0);
        acc = __builtin_amdgcn_mfma_f32_16x16x32_bf16(al[rt][0], bh0, acc, 0, 0, 0);
        acc = __builtin_amdgcn_mfma_f32_16x16x32_bf16(al[rt][1], bh1, acc, 0, 0, 0);
        acc = __builtin_amdgcn_mfma_f32_16x16x32_bf16(ah[rt][0], bl0, acc, 0, 0, 0);
        acc = __builtin_amdgcn_mfma_f32_16x16x32_bf16(ah[rt][1], bl1, acc, 0, 0, 0);
        #pragma unroll
        for (int i = 0; i < 4; i++) {   // C layout: col=lane&15(code), row=(lane>>4)*4+i
          const float dist4 = fmaf(-2.0f, acc[i], skv4);              // sk+4-2dot
          const unsigned key = (__float_as_uint(dist4) & 0xFFFFFC00u) | codev;
          const int s = rt * 4 + i;
          unsigned m;   // med3(k1,k2,key) == new 2nd-best given k1<=k2
          asm("v_med3_u32 %0, %1, %2, %3" : "=v"(m) : "v"(k1[s]), "v"(k2[s]), "v"(key));
          k2[s] = m;
          k1[s] = (key < k1[s]) ? key : k1[s];
        }
      }
    }
  }

  // ---- per-row top-2 reduce across the 16 lanes of each group ----
  #pragma unroll
  for (int s = 0; s < 8; s++) {
    unsigned a = k1[s], bb = k2[s];
    #pragma unroll
    for (int m = 1; m < 16; m <<= 1) {
      const unsigned pa = (unsigned)__shfl_xor((int)a, m, 64);
      const unsigned pb = (unsigned)__shfl_xor((int)bb, m, 64);
      const unsigned mx = (a > pa) ? a : pa;
      const unsigned mn2 = (bb < pb) ? bb : pb;
      bb = (mn2 < mx) ? mn2 : mx;
      a = (a < pa) ? a : pa;   // distinct code bits => strict order; min = smaller code
    }
    if ((lane & 15) == 0) {
      const int row_local = wave * 32 + (s >> 2) * 16 + (lane >> 4) * 4 + (s & 3);
      ib[row_local] = (int)(a & 1023u);
      // approx SSE: quantized dist (+half-bin recenter) + row c
      rowsse[row_local] = __uint_as_float(a & 0xFFFFFC00u) - 4.0f + c_arr[row_local]
                          + 2.44140625e-4f;
      if (((bb >> 10) - (a >> 10)) < 2u) {   // same/adjacent bin -> exact recheck
        qlist[atomicAdd(&qn_s, 1)] = row_local;
      }
    }
  }
  __syncthreads();

  // ---- block-local exact refine: one wave per queued row, fp32 full scan ----
  const int qn = qn_s;
  for (int qi = wave; qi < qn; qi += 4) {
    const int rl = qlist[qi];
    const size_t row = (size_t)blockIdx.x * 128 + rl;
    const float4* xr = (const float4*)(x + row * DIM);
    float4 xv[16];
    float ss = 0.f;
    #pragma unroll
    for (int i = 0; i < 16; i++) {
      xv[i] = xr[i];
      ss += xv[i].x * xv[i].x + xv[i].y * xv[i].y + xv[i].z * xv[i].z + xv[i].w * xv[i].w;
    }
    const float den = fmaxf(sqrtf(ss), 1e-12f);
    #pragma unroll
    for (int i = 0; i < 16; i++) { xv[i].x /= den; xv[i].y /= den; xv[i].z /= den; xv[i].w /= den; }
    float cc = 0.f;
    #pragma unroll
    for (int i = 0; i < 16; i++)
      cc += xv[i].x * xv[i].x + xv[i].y * xv[i].y + xv[i].z * xv[i].z + xv[i].w * xv[i].w;

    float best = INFINITY;
    int bidx = 0x7FFFFFFF;
    for (int j = 0; j < 16; j++) {
      const int k = j * 64 + lane;
      const float4* wr = (const float4*)(wn + (size_t)k * DIM);
      float d0 = 0.f, d1 = 0.f, d2 = 0.f, d3 = 0.f;
      #pragma unroll
      for (int i = 0; i < 16; i++) {
        const float4 wv = wr[i];
        d0 = fmaf(xv[i].x, wv.x, d0);
        d1 = fmaf(xv[i].y, wv.y, d1);
        d2 = fmaf(xv[i].z, wv.z, d2);
        d3 = fmaf(xv[i].w, wv.w, d3);
      }
      const float dot = (d0 + d1) + (d2 + d3);
      const float dist = (cc + sk[k]) - 2.0f * dot;
      if (dist < best) { best = dist; bidx = k; }   // per-lane ascending k
    }
    #pragma unroll
    for (int m = 1; m < 64; m <<= 1) {
      const float pb = __shfl_xor(best, m, 64);
      const int pi = __shfl_xor(bidx, m, 64);
      if (pb < best || (pb == best && pi < bidx)) { best = pb; bidx = pi; }  // first-occurrence
    }
    if (lane == 0) { ib[rl] = bidx; rowsse[rl] = best; }
  }
  __syncthreads();

  // ---- bookkeeping with FINAL indices ----
  if (tid < 128) {
    const size_t row = (size_t)blockIdx.x * 128 + tid;
    const int idx = ib[tid];
    out[OUT_IDX_OFF + row] = (float)idx;
    atomicAdd(&counts[idx], 1u);
  }

  // quantized write: 128 rows x 64 elems; per wave-iter one wn row (broadcast)
  const size_t obase = OUT_Q_OFF + (size_t)blockIdx.x * (128 * DIM);
  #pragma unroll 4
  for (int j = 0; j < 32; j++) {
    const int e = j * 256 + tid;           // e>>6 wave-uniform
    out[obase + e] = wn[(size_t)ib[e >> 6] * DIM + (e & 63)];
  }

  // block SSE reduction -> one global atomic
  __syncthreads();
  for (int s = 64; s > 0; s >>= 1) {
    if (tid < s && tid + s < 128) rowsse[tid] += rowsse[tid + s];
    __syncthreads();
  }
  if (tid == 0) atomicAdd(sse_accum, rowsse[0]);

  // ---- last-block-done finalize ----
  if (tid == 0) {
    __threadfence();                          // release: counts/sse visible device-wide
    islast = (atomicAdd(done, 1u) == NBLOCKS - 1) ? 1 : 0;
  }
  __syncthreads();
  if (islast) {
    __threadfence();                          // acquire side
    float h = 0.f;
    #pragma unroll
    for (int i = 0; i < 4; i++) {
      const float cv = (float)counts[tid * 4 + i];
      const float avg = cv * (1.0f / (float)NROWS);
      h += avg * logf(avg + 1e-10f);
    }
    #pragma unroll
    for (int o = 32; o > 0; o >>= 1) h += __shfl_xor(h, o, 64);
    __shared__ float hred[4];
    if (lane == 0) hred[wave] = h;
    __syncthreads();
    if (tid == 0) {
      const float H = -(hred[0] + hred[1] + hred[2] + hred[3]);
      const float mse = *sse_accum * (1.0f / (float)((size_t)NROWS * DIM));
      out[0] = mse + 0.25f * mse;             // == 1.25*mse in fp32
      out[OUT_PERP_OFF] = expf(H);
    }
  }
}

extern "C" void kernel_launch(void* const* d_in, const int* in_sizes, int n_in,
                              void* d_out, int out_size, void* d_ws, size_t ws_size,
                              hipStream_t stream) {
  const float* x = (const float*)d_in[0];   // [16,4096,64] fp32
  const float* w = (const float*)d_in[1];   // [1024,64] fp32
  float* out = (float*)d_out;

  char* ws = (char*)d_ws;
  unsigned* counts    = (unsigned*)(ws + WS_COUNTS);
  float* sse_accum    = (float*)(ws + WS_SSEC);
  unsigned* done      = (unsigned*)(ws + WS_DONE);
  float* wn           = (float*)(ws + WS_WN);
  float* sk           = (float*)(ws + WS_SK);
  unsigned short* wnh = (unsigned short*)(ws + WS_WNH);
  unsigned short* wnl = (unsigned short*)(ws + WS_WNL);

  // 2 dispatches total; normalize kernel zeroes counts/sse/done (stream-ordered
  // before the mega kernel; ws is re-poisoned 0xAA before every call).
  normalize_w_kernel<<<KCODES, 64, 0, stream>>>(w, wn, sk, wnh, wnl,
                                                counts, sse_accum, done);
  vq_mega_kernel<<<NBLOCKS, 256, 0, stream>>>(
      x, wnh, wnl, sk, wn, out, counts, sse_accum, done);
}

// Round 7
// 144.808 us; speedup vs baseline: 1.2138x; 1.2138x over previous
//
#include <hip/hip_runtime.h>
#include <hip/hip_bf16.h>
#include <math.h>

// Problem constants (fixed by the reference)
#define NROWS   65536          // 16*4096 flattened rows
#define DIM     64             // embedding dim
#define KCODES  1024           // num embeddings
#define NBLOCKS (NROWS / 128)  // 512 mega-kernel blocks

// Fallback threshold: queue a row iff (d2 - d1) < QGAP. Filter dist error vs
// fp32 reference: split-2 bf16 residuals (missing xl*wl <= 2^-18, rounding
// ~2^-18) + fp32 accumulation-order diff (~1e-6 RMS) => <= ~3e-5 realistic,
// 6e-5 paranoid. 1.25e-4 keeps >=2x margin while cutting the queue ~6x vs R6.
#define QGAP 1.25e-4f

typedef short short8 __attribute__((ext_vector_type(8)));   // 8 bf16 = 4 VGPR (MFMA A/B frag)
typedef float f32x4  __attribute__((ext_vector_type(4)));   // MFMA C/D frag

// Output layout (floats), reference return order:
//   out[0] loss | out[1..] quantized (N*D) | perplexity | indices (as float)
#define OUT_Q_OFF    ((size_t)1)
#define OUT_PERP_OFF ((size_t)(1 + (size_t)NROWS * DIM))
#define OUT_IDX_OFF  ((size_t)(2 + (size_t)NROWS * DIM))

// Workspace layout (bytes); zeroing done by normalize_w_kernel (stream-ordered)
#define WS_COUNTS 0                         // unsigned[1024]
#define WS_SSEC   4096                      // float   (global SSE accumulator)
#define WS_DONE   4100                      // unsigned (blocks-done counter)
#define WS_WN     8192                      // float wn[1024*64]
#define WS_SK     (WS_WN + KCODES*DIM*4)    // float sk[1024]
#define WS_WNH    (WS_SK + KCODES*4)        // ushort wnh[1024*64]
#define WS_WNL    (WS_WNH + KCODES*DIM*2)   // ushort wnl[1024*64]

__device__ __forceinline__ unsigned short bf16_rne(float f) {
  unsigned u = __float_as_uint(f);
  return (unsigned short)((u + 0x7FFFu + ((u >> 16) & 1u)) >> 16);
}
__device__ __forceinline__ float bf16f(unsigned short h) {
  return __uint_as_float(((unsigned)h) << 16);
}

// Normalize codebook + split to bf16 hi/lo + zero the mega-kernel's counters.
__global__ void __launch_bounds__(64) normalize_w_kernel(
    const float* __restrict__ w, float* __restrict__ wn, float* __restrict__ sk,
    unsigned short* __restrict__ wnh, unsigned short* __restrict__ wnl,
    unsigned* __restrict__ counts, float* __restrict__ sse_accum,
    unsigned* __restrict__ done) {
  const int k = blockIdx.x;   // one code per 64-lane wave
  const int d = threadIdx.x;
  if (d == 0) {
    counts[k] = 0u;                                   // 1024 blocks cover counts[1024]
    if (k == 0) { *sse_accum = 0.f; *done = 0u; }
  }
  float v = w[k * DIM + d];
  float ss = v * v;
  #pragma unroll
  for (int o = 32; o > 0; o >>= 1) ss += __shfl_xor(ss, o, 64);
  const float den = fmaxf(sqrtf(ss), 1e-12f);
  const float q = v / den;                 // true division: hug reference rounding
  wn[k * DIM + d] = q;
  const unsigned short h = bf16_rne(q);
  wnh[k * DIM + d] = h;
  wnl[k * DIM + d] = bf16_rne(q - bf16f(h));
  float s2 = q * q;
  #pragma unroll
  for (int o = 32; o > 0; o >>= 1) s2 += __shfl_xor(s2, o, 64);
  if (d == 0) sk[k] = s2;
}

// Mega-kernel: split-2 bf16 MFMA filter (exact fp32 top-2 tracking) +
// block-local exact refine + all bookkeeping + last-block finalize.
// Block = 256 thr (4 waves) = 128 rows.
__global__ void __launch_bounds__(256) vq_mega_kernel(
    const float* __restrict__ x, const unsigned short* __restrict__ wnh,
    const unsigned short* __restrict__ wnl, const float* __restrict__ sk,
    const float* __restrict__ wn, float* __restrict__ out,
    unsigned* __restrict__ counts, float* __restrict__ sse_accum,
    unsigned* __restrict__ done) {
  // AB union: phase A: Ah=[0,4608) Al=[4608,9216) u32 (128 rows x 36 u32)
  //           phase B: buf b at b*4608: Bh=[+0,+2304) Bl=[+2304,+4608)
  __shared__ unsigned AB[9216];
  __shared__ float skb[2][64];     // staged sk per chunk
  __shared__ float c_arr[128];     // ||xn||^2 per row
  __shared__ float rowsse[128];    // per-row SSE (filter-approx; exact if refined)
  __shared__ int   ib[128];        // per-row final idx
  __shared__ int   qlist[128];     // block-local refine queue (row_local)
  __shared__ int   qn_s;
  __shared__ int   islast;
  const int tid = threadIdx.x;
  const int lane = tid & 63, wave = tid >> 6;

  if (tid == 0) qn_s = 0;

  // ---- phase 1: threads 0..127 normalize one row each, split to bf16 hi/lo ----
  if (tid < 128) {
    const size_t row = (size_t)blockIdx.x * 128 + tid;
    const float4* xr = (const float4*)(x + row * DIM);
    float4 xv[16];
    float ss = 0.f;
    #pragma unroll
    for (int i = 0; i < 16; i++) {
      xv[i] = xr[i];
      ss += xv[i].x * xv[i].x + xv[i].y * xv[i].y + xv[i].z * xv[i].z + xv[i].w * xv[i].w;
    }
    const float inv = 1.0f / fmaxf(sqrtf(ss), 1e-12f);   // mul-normalize: filter only
    float c = 0.f;
    #pragma unroll
    for (int i = 0; i < 16; i++) {
      const float a0 = xv[i].x * inv, a1 = xv[i].y * inv;
      const float a2 = xv[i].z * inv, a3 = xv[i].w * inv;
      c += a0 * a0 + a1 * a1 + a2 * a2 + a3 * a3;
      const unsigned short h0 = bf16_rne(a0), h1 = bf16_rne(a1);
      const unsigned short h2 = bf16_rne(a2), h3 = bf16_rne(a3);
      const unsigned short l0 = bf16_rne(a0 - bf16f(h0)), l1 = bf16_rne(a1 - bf16f(h1));
      const unsigned short l2 = bf16_rne(a2 - bf16f(h2)), l3 = bf16_rne(a3 - bf16f(h3));
      AB[tid * 36 + 2 * i]            = (unsigned)h0 | ((unsigned)h1 << 16);
      AB[tid * 36 + 2 * i + 1]        = (unsigned)h2 | ((unsigned)h3 << 16);
      AB[4608 + tid * 36 + 2 * i]     = (unsigned)l0 | ((unsigned)l1 << 16);
      AB[4608 + tid * 36 + 2 * i + 1] = (unsigned)l2 | ((unsigned)l3 << 16);
    }
    c_arr[tid] = c;
  }
  __syncthreads();

  // ---- A fragments -> registers (A[m=lane&15][k=(lane>>4)*8+j]) ----
  short8 ah[2][2], al[2][2];
  #pragma unroll
  for (int rt = 0; rt < 2; rt++)
    #pragma unroll
    for (int kk = 0; kk < 2; kk++) {
      const int r = wave * 32 + rt * 16 + (lane & 15);
      ah[rt][kk] = *(const short8*)&AB[r * 36 + kk * 16 + (lane >> 4) * 4];
      al[rt][kk] = *(const short8*)&AB[4608 + r * 36 + kk * 16 + (lane >> 4) * 4];
    }
  __syncthreads();   // A region now dead -> becomes B double-buffer

  // per-slot exact fp32 top-2: d1 (best), i1 (its code), d2 (second-best)
  float d1[8], d2[8];
  int   i1[8];
  #pragma unroll
  for (int s = 0; s < 8; s++) { d1[s] = INFINITY; d2[s] = INFINITY; i1[s] = 0x7FFFFFFF; }

  // stage chunk 0 into buf 0
  {
    const int code = tid >> 2, q = tid & 3;
    const float4* gh = (const float4*)(wnh + (size_t)code * DIM + q * 16);
    const float4* gl = (const float4*)(wnl + (size_t)code * DIM + q * 16);
    float4* dh = (float4*)&AB[code * 36 + q * 8];
    float4* dl = (float4*)&AB[2304 + code * 36 + q * 8];
    dh[0] = gh[0]; dh[1] = gh[1];
    dl[0] = gl[0]; dl[1] = gl[1];
    if (tid < 64) skb[0][tid] = sk[tid];
  }

  #pragma unroll 2
  for (int c = 0; c < 16; c++) {
    const int b = c & 1;
    __syncthreads();   // buf b fully staged; buf b^1 free to overwrite
    if (c < 15) {      // stage next chunk (loads fly during compute below)
      const int nb = b ^ 1;
      const int code = tid >> 2, q = tid & 3;
      const float4* gh = (const float4*)(wnh + (size_t)((c + 1) * 64 + code) * DIM + q * 16);
      const float4* gl = (const float4*)(wnl + (size_t)((c + 1) * 64 + code) * DIM + q * 16);
      float4* dh = (float4*)&AB[nb * 4608 + code * 36 + q * 8];
      float4* dl = (float4*)&AB[nb * 4608 + 2304 + code * 36 + q * 8];
      dh[0] = gh[0]; dh[1] = gh[1];
      dl[0] = gl[0]; dl[1] = gl[1];
      if (tid < 64) skb[nb][tid] = sk[(c + 1) * 64 + tid];
    }
    #pragma unroll
    for (int tt = 0; tt < 4; tt++) {
      const int cb = tt * 16 + (lane & 15);       // code within chunk (B col)
      const float skv = skb[b][cb];
      const int codev = c * 64 + cb;
      const short8 bh0 = *(const short8*)&AB[b * 4608 + cb * 36 + 0 * 16 + (lane >> 4) * 4];
      const short8 bh1 = *(const short8*)&AB[b * 4608 + cb * 36 + 1 * 16 + (lane >> 4) * 4];
      const short8 bl0 = *(const short8*)&AB[b * 4608 + 2304 + cb * 36 + 0 * 16 + (lane >> 4) * 4];
      const short8 bl1 = *(const short8*)&AB[b * 4608 + 2304 + cb * 36 + 1 * 16 + (lane >> 4) * 4];
      #pragma unroll
      for (int rt = 0; rt < 2; rt++) {
        f32x4 acc = {0.f, 0.f, 0.f, 0.f};
        acc = __builtin_amdgcn_mfma_f32_16x16x32_bf16(ah[rt][0], bh0, acc, 0, 0, 0);
        acc = __builtin_amdgcn_mfma_f32_16x16x32_bf16(ah[rt][1], bh1, acc, 0, 0, 0);
        acc = __builtin_amdgcn_mfma_f32_16x16x32_bf16(al[rt][0], bh0, acc, 0, 0, 0);
        acc = __builtin_amdgcn_mfma_f32_16x16x32_bf16(al[rt][1], bh1, acc, 0, 0, 0);
        acc = __builtin_amdgcn_mfma_f32_16x16x32_bf16(ah[rt][0], bl0, acc, 0, 0, 0);
        acc = __builtin_amdgcn_mfma_f32_16x16x32_bf16(ah[rt][1], bl1, acc, 0, 0, 0);
        #pragma unroll
        for (int i = 0; i < 4; i++) {   // C layout: col=lane&15(code), row=(lane>>4)*4+i
          const float dist = fmaf(-2.0f, acc[i], skv);   // sk - 2*dot (row c uniform: dropped)
          const int s = rt * 4 + i;
          // med3(d1,d2,dist) == new second-best given d1<=d2
          d2[s] = __builtin_amdgcn_fmed3f(d1[s], d2[s], dist);
          const bool take = dist < d1[s];
          d1[s] = take ? dist : d1[s];
          i1[s] = take ? codev : i1[s];
        }
      }
    }
  }

  // ---- per-row top-2 reduce across the 16 lanes of each group ----
  #pragma unroll
  for (int s = 0; s < 8; s++) {
    float a1 = d1[s], a2 = d2[s];
    int   ai = i1[s];
    #pragma unroll
    for (int m = 1; m < 16; m <<= 1) {
      const float p1 = __shfl_xor(a1, m, 64);
      const float p2 = __shfl_xor(a2, m, 64);
      const int   pi = __shfl_xor(ai, m, 64);
      const float mx = fmaxf(a1, p1);
      a2 = fminf(fminf(a2, p2), mx);
      const bool take = (p1 < a1) || (p1 == a1 && pi < ai);  // first-occurrence on ties
      a1 = take ? p1 : a1;
      ai = take ? pi : ai;
    }
    if ((lane & 15) == 0) {
      const int row_local = wave * 32 + (s >> 2) * 16 + (lane >> 4) * 4 + (s & 3);
      ib[row_local] = ai;
      rowsse[row_local] = a1 + c_arr[row_local];   // ||xn-q||^2, filter-accurate (~2e-5)
      if (a2 - a1 < QGAP) qlist[atomicAdd(&qn_s, 1)] = row_local;
    }
  }
  __syncthreads();

  // ---- block-local exact refine: one wave per queued row, fp32 full scan ----
  const int qn = qn_s;
  for (int qi = wave; qi < qn; qi += 4) {
    const int rl = qlist[qi];
    const size_t row = (size_t)blockIdx.x * 128 + rl;
    const float4* xr = (const float4*)(x + row * DIM);
    float4 xv[16];
    float ss = 0.f;
    #pragma unroll
    for (int i = 0; i < 16; i++) {
      xv[i] = xr[i];
      ss += xv[i].x * xv[i].x + xv[i].y * xv[i].y + xv[i].z * xv[i].z + xv[i].w * xv[i].w;
    }
    const float den = fmaxf(sqrtf(ss), 1e-12f);
    #pragma unroll
    for (int i = 0; i < 16; i++) { xv[i].x /= den; xv[i].y /= den; xv[i].z /= den; xv[i].w /= den; }
    float cc = 0.f;
    #pragma unroll
    for (int i = 0; i < 16; i++)
      cc += xv[i].x * xv[i].x + xv[i].y * xv[i].y + xv[i].z * xv[i].z + xv[i].w * xv[i].w;

    float best = INFINITY;
    int bidx = 0x7FFFFFFF;
    for (int j = 0; j < 16; j++) {
      const int k = j * 64 + lane;
      const float4* wr = (const float4*)(wn + (size_t)k * DIM);
      float e0 = 0.f, e1 = 0.f, e2 = 0.f, e3 = 0.f;
      #pragma unroll
      for (int i = 0; i < 16; i++) {
        const float4 wv = wr[i];
        e0 = fmaf(xv[i].x, wv.x, e0);
        e1 = fmaf(xv[i].y, wv.y, e1);
        e2 = fmaf(xv[i].z, wv.z, e2);
        e3 = fmaf(xv[i].w, wv.w, e3);
      }
      const float dot = (e0 + e1) + (e2 + e3);
      const float dist = (cc + sk[k]) - 2.0f * dot;
      if (dist < best) { best = dist; bidx = k; }   // per-lane ascending k
    }
    #pragma unroll
    for (int m = 1; m < 64; m <<= 1) {
      const float pb = __shfl_xor(best, m, 64);
      const int pi = __shfl_xor(bidx, m, 64);
      if (pb < best || (pb == best && pi < bidx)) { best = pb; bidx = pi; }  // first-occurrence
    }
    if (lane == 0) { ib[rl] = bidx; rowsse[rl] = best; }
  }
  __syncthreads();

  // ---- bookkeeping with FINAL indices ----
  if (tid < 128) {
    const size_t row = (size_t)blockIdx.x * 128 + tid;
    const int idx = ib[tid];
    out[OUT_IDX_OFF + row] = (float)idx;
    atomicAdd(&counts[idx], 1u);
  }

  // quantized write: 128 rows x 64 elems; per wave-iter one wn row (broadcast)
  const size_t obase = OUT_Q_OFF + (size_t)blockIdx.x * (128 * DIM);
  #pragma unroll 4
  for (int j = 0; j < 32; j++) {
    const int e = j * 256 + tid;           // e>>6 wave-uniform
    out[obase + e] = wn[(size_t)ib[e >> 6] * DIM + (e & 63)];
  }

  // block SSE reduction -> one global atomic
  __syncthreads();
  for (int s = 64; s > 0; s >>= 1) {
    if (tid < s && tid + s < 128) rowsse[tid] += rowsse[tid + s];
    __syncthreads();
  }
  if (tid == 0) atomicAdd(sse_accum, rowsse[0]);

  // ---- last-block-done finalize ----
  if (tid == 0) {
    __threadfence();                          // release: counts/sse visible device-wide
    islast = (atomicAdd(done, 1u) == NBLOCKS - 1) ? 1 : 0;
  }
  __syncthreads();
  if (islast) {
    __threadfence();                          // acquire side
    float h = 0.f;
    #pragma unroll
    for (int i = 0; i < 4; i++) {
      const float cv = (float)counts[tid * 4 + i];
      const float avg = cv * (1.0f / (float)NROWS);
      h += avg * logf(avg + 1e-10f);
    }
    #pragma unroll
    for (int o = 32; o > 0; o >>= 1) h += __shfl_xor(h, o, 64);
    __shared__ float hred[4];
    if (lane == 0) hred[wave] = h;
    __syncthreads();
    if (tid == 0) {
      const float H = -(hred[0] + hred[1] + hred[2] + hred[3]);
      const float mse = *sse_accum * (1.0f / (float)((size_t)NROWS * DIM));
      out[0] = mse + 0.25f * mse;             // == 1.25*mse in fp32
      out[OUT_PERP_OFF] = expf(H);
    }
  }
}

extern "C" void kernel_launch(void* const* d_in, const int* in_sizes, int n_in,
                              void* d_out, int out_size, void* d_ws, size_t ws_size,
                              hipStream_t stream) {
  const float* x = (const float*)d_in[0];   // [16,4096,64] fp32
  const float* w = (const float*)d_in[1];   // [1024,64] fp32
  float* out = (float*)d_out;

  char* ws = (char*)d_ws;
  unsigned* counts    = (unsigned*)(ws + WS_COUNTS);
  float* sse_accum    = (float*)(ws + WS_SSEC);
  unsigned* done      = (unsigned*)(ws + WS_DONE);
  float* wn           = (float*)(ws + WS_WN);
  float* sk           = (float*)(ws + WS_SK);
  unsigned short* wnh = (unsigned short*)(ws + WS_WNH);
  unsigned short* wnl = (unsigned short*)(ws + WS_WNL);

  // 2 dispatches total; normalize kernel zeroes counts/sse/done (stream-ordered
  // before the mega kernel; ws is re-poisoned 0xAA before every call).
  normalize_w_kernel<<<KCODES, 64, 0, stream>>>(w, wn, sk, wnh, wnl,
                                                counts, sse_accum, done);
  vq_mega_kernel<<<NBLOCKS, 256, 0, stream>>>(
      x, wnh, wnl, sk, wn, out, counts, sse_accum, done);
}